// Round 19
// baseline (109.650 us; speedup 1.0000x reference)
//
#include <hip/hip_runtime.h>
#include <math.h>

#define I_N 64
#define Q_N 49
#define T_N 64
#define S_N 64
#define D_N 256

typedef __attribute__((ext_vector_type(8))) short short8;
typedef __attribute__((ext_vector_type(4))) short s16x4;
typedef __attribute__((ext_vector_type(4))) float f32x4;
typedef unsigned short ushort_t;

__device__ __forceinline__ float waveReduceSum64(float v) {
    v += __shfl_xor(v, 1);
    v += __shfl_xor(v, 2);
    v += __shfl_xor(v, 4);
    v += __shfl_xor(v, 8);
    v += __shfl_xor(v, 16);
    v += __shfl_xor(v, 32);
    return v;
}

__device__ __forceinline__ ushort_t f2bf(float x) {
    unsigned u = __builtin_bit_cast(unsigned, x);
    unsigned r = (u + 0x7fffu + ((u >> 16) & 1u)) >> 16;
    return (ushort_t)r;
}
__device__ __forceinline__ float bf2f(ushort_t h) {
    unsigned u = ((unsigned)h) << 16;
    return __builtin_bit_cast(float, u);
}
__device__ __forceinline__ void split_bf16(float x, ushort_t& h, ushort_t& l) {
    h = f2bf(x);
    l = f2bf(x - bf2f(h));
}

// ---------- fused prep: one launch, routed by blockIdx (round-18 exact) ----------
__global__ void prep_all(const float* __restrict__ q_in, const float* __restrict__ v_in,
                         const float* __restrict__ k_in, const float* __restrict__ tv,
                         ushort_t* __restrict__ qfh, ushort_t* __restrict__ qfl,
                         ushort_t* __restrict__ kfh, ushort_t* __restrict__ kfl,
                         ushort_t* __restrict__ vfh, ushort_t* __restrict__ vfl,
                         float* __restrict__ vP, float* __restrict__ vnorm) {
    __shared__ float tile[64][65];
    __shared__ float ws[8];
    int b = blockIdx.x;
    int tid = threadIdx.x;

    if (b < 8192) {
        int isimg = (b < 4096) ? 1 : 0;
        int row = isimg ? b : (b - 4096);      // hi*64 + lo
        int hi = row >> 6, lo = row & 63;
        float x = 0.0f, vv = 0.0f;
        if (isimg) {
            if (lo < Q_N) {
                size_t base = ((size_t)hi * Q_N + lo) * D_N + tid;
                x = q_in[base];
                vv = v_in[base];
            }
        } else {
            x = k_in[(size_t)row * D_N + tid];
        }
        float s1 = waveReduceSum64(x * x);
        float s2 = waveReduceSum64(vv * vv);
        int wv = tid >> 6, ln = tid & 63;
        if (ln == 0) { ws[wv] = s1; ws[4 + wv] = s2; }
        __syncthreads();
        float n1 = sqrtf(ws[0] + ws[1] + ws[2] + ws[3]);
        float xn = x / fmaxf(n1, 1e-12f);
        ushort_t h, l;
        split_bf16(xn, h, l);
        size_t off = ((size_t)hi << 14) + (size_t)((((lo >> 4) * 8 + (tid >> 5))) << 9)
                   + (size_t)(((((tid >> 3) & 3) * 16 + (lo & 15))) << 3) + (tid & 7);
        if (isimg) {
            qfh[off] = h;
            qfl[off] = l;
            if (tid == 0) vnorm[row] = sqrtf(ws[4] + ws[5] + ws[6] + ws[7]);
        } else {
            kfh[off] = h;
            kfl[off] = l;
        }
    } else if (b < 8448) {
        int bb = b - 8192;
        int t = bb >> 2;
        int d0 = (bb & 3) * 64;
        const float* src = tv + ((size_t)t << 14) + d0;
        ushort_t* dh = vfh + ((size_t)t << 14);
        ushort_t* dl = vfl + ((size_t)t << 14);
#pragma unroll
        for (int r = 0; r < 16; ++r) {
            int idx = r * 256 + tid;
            int s = idx >> 6, d = idx & 63;
            tile[s][d] = src[s * D_N + d];
        }
        __syncthreads();
#pragma unroll
        for (int r = 0; r < 16; ++r) {
            int idx = r * 256 + tid;
            int d = idx >> 6, s = idx & 63;
            int dg = d0 + d;
            float x = tile[s][d];
            ushort_t h, l;
            split_bf16(x, h, l);
            int dgrp = dg >> 4, lrd = dg & 15;
            int k0g = s >> 5, lk3 = (s >> 3) & 3, e = s & 7;
            size_t off = (size_t)(dgrp << 10) + (k0g << 9) + ((lk3 * 16 + lrd) << 3) + e;
            dh[off] = h;
            dl[off] = l;
        }
    } else {
        int bb = b - 8448;
        int i = bb >> 3;
        int sub = bb & 7;
        const float* src = v_in + (size_t)i * Q_N * D_N;
        float* dst = vP + ((size_t)i << 14);
#pragma unroll
        for (int r2 = 0; r2 < 8; ++r2) {
            int rep = sub * 8 + r2;             // 0..63
            int o = rep * 256 + tid;
            int r = o & 3;
            int md = (o >> 2) & 3;
            int nq = (o >> 4) & 3;
            int lane = (o >> 6) & 63;
            int w = o >> 12;
            int lr = lane & 15, lk = lane >> 4;
            int q = nq * 16 + lr;
            int d = w * 64 + md * 16 + lk * 4 + r;
            dst[o] = (q < Q_N) ? src[q * D_N + d] : 0.0f;
        }
    }
}

// ---------- main: 4 waves per (t,i); in-register softmax, 19.5KB LDS ----------
// LDS: Ph @0 (8K) | Pl @8192 (8K) | rowp @16384 (512B) | colp @16896 (1K: csum,sk)
//      wsq @17920 (1K) | wdv @18944 (1K)
__launch_bounds__(256, 4)
__global__ void i2t_mfma(const ushort_t* __restrict__ kfh, const ushort_t* __restrict__ kfl,
                         const ushort_t* __restrict__ qfh, const ushort_t* __restrict__ qfl,
                         const ushort_t* __restrict__ vfh, const ushort_t* __restrict__ vfl,
                         const float* __restrict__ vP,
                         const float* __restrict__ vnorm,
                         const int* __restrict__ tlen,
                         float* __restrict__ out)
{
    __shared__ __align__(16) unsigned char RK[19968];

    const int bid = blockIdx.x;
    const int xcd = bid & 7;
    const int j = bid >> 3;
    const int t = (xcd << 3) | (j & 7);   // each XCD owns 8 t values -> K/Vf L2-resident
    const int i = j >> 3;

    const int tid = threadIdx.x;
    const int lane = tid & 63;
    const int w = tid >> 6;        // wave 0..3
    const int lr = lane & 15;
    const int lk = lane >> 4;

    // ============ Phase 1: attn[s][q] = K.Q^T, wave tile = 32s x 32q (2x2 subtiles) ====
    const int wsr = (w >> 1) * 32;    // s-base
    const int wq  = (w & 1) * 32;     // q-base
    f32x4 acc[2][2];
#pragma unroll
    for (int a = 0; a < 2; ++a)
#pragma unroll
        for (int b2 = 0; b2 < 2; ++b2) acc[a][b2] = (f32x4){0.f, 0.f, 0.f, 0.f};
    {
        const ushort_t* kH = kfh + ((size_t)t << 14) + (size_t)(w >> 1) * 8192;
        const ushort_t* kL = kfl + ((size_t)t << 14) + (size_t)(w >> 1) * 8192;
        const ushort_t* qH = qfh + ((size_t)i << 14) + (size_t)(w & 1) * 8192;
        const ushort_t* qL = qfl + ((size_t)i << 14) + (size_t)(w & 1) * 8192;
#pragma unroll
        for (int k8 = 0; k8 < 8; ++k8) {
            int fo = k8 * 512 + lane * 8;
            short8 aH0 = *(const short8*)(kH + fo);
            short8 aL0 = *(const short8*)(kL + fo);
            short8 aH1 = *(const short8*)(kH + 4096 + fo);
            short8 aL1 = *(const short8*)(kL + 4096 + fo);
            short8 bH0 = *(const short8*)(qH + fo);
            short8 bL0 = *(const short8*)(qL + fo);
            short8 bH1 = *(const short8*)(qH + 4096 + fo);
            short8 bL1 = *(const short8*)(qL + 4096 + fo);
            acc[0][0] = __builtin_amdgcn_mfma_f32_16x16x32_bf16(aH0, bH0, acc[0][0], 0, 0, 0);
            acc[0][1] = __builtin_amdgcn_mfma_f32_16x16x32_bf16(aH0, bH1, acc[0][1], 0, 0, 0);
            acc[1][0] = __builtin_amdgcn_mfma_f32_16x16x32_bf16(aH1, bH0, acc[1][0], 0, 0, 0);
            acc[1][1] = __builtin_amdgcn_mfma_f32_16x16x32_bf16(aH1, bH1, acc[1][1], 0, 0, 0);
            acc[0][0] = __builtin_amdgcn_mfma_f32_16x16x32_bf16(aH0, bL0, acc[0][0], 0, 0, 0);
            acc[0][1] = __builtin_amdgcn_mfma_f32_16x16x32_bf16(aH0, bL1, acc[0][1], 0, 0, 0);
            acc[1][0] = __builtin_amdgcn_mfma_f32_16x16x32_bf16(aH1, bL0, acc[1][0], 0, 0, 0);
            acc[1][1] = __builtin_amdgcn_mfma_f32_16x16x32_bf16(aH1, bL1, acc[1][1], 0, 0, 0);
            acc[0][0] = __builtin_amdgcn_mfma_f32_16x16x32_bf16(aL0, bH0, acc[0][0], 0, 0, 0);
            acc[0][1] = __builtin_amdgcn_mfma_f32_16x16x32_bf16(aL0, bH1, acc[0][1], 0, 0, 0);
            acc[1][0] = __builtin_amdgcn_mfma_f32_16x16x32_bf16(aL1, bH0, acc[1][0], 0, 0, 0);
            acc[1][1] = __builtin_amdgcn_mfma_f32_16x16x32_bf16(aL1, bH1, acc[1][1], 0, 0, 0);
        }
    }

    // ============ Phase 2 (in-register): LeakyReLU, row-l2norm, softmax, focal ========
    // LeakyReLU
#pragma unroll
    for (int si = 0; si < 2; ++si)
#pragma unroll
        for (int qi = 0; qi < 2; ++qi)
#pragma unroll
            for (int r = 0; r < 4; ++r) {
                float v = acc[si][qi][r];
                acc[si][qi][r] = (v > 0.0f) ? v : 0.1f * v;
            }

    // row l2norm over q: own 32 cols (xor 1..8) + exchange with wave w^1.
    // row s = wsr + si*16 + lk*4 + r; row-local index ri = si*16 + lk*4 + r.
    {
        float* rowp = (float*)(RK + 16384);
        float ssv[2][4];
#pragma unroll
        for (int si = 0; si < 2; ++si)
#pragma unroll
            for (int r = 0; r < 4; ++r) {
                float v0 = acc[si][0][r], v1 = acc[si][1][r];
                float ss = v0 * v0 + v1 * v1;
                ss += __shfl_xor(ss, 1);
                ss += __shfl_xor(ss, 2);
                ss += __shfl_xor(ss, 4);
                ss += __shfl_xor(ss, 8);
                ssv[si][r] = ss;
            }
        if (lr == 0) {
#pragma unroll
            for (int si = 0; si < 2; ++si)
#pragma unroll
                for (int r = 0; r < 4; ++r)
                    rowp[w * 32 + si * 16 + lk * 4 + r] = ssv[si][r];
        }
        __syncthreads();
        const float* prp = (const float*)(RK + 16384) + (w ^ 1) * 32;
#pragma unroll
        for (int si = 0; si < 2; ++si)
#pragma unroll
            for (int r = 0; r < 4; ++r) {
                float tot = ssv[si][r] + prp[si * 16 + lk * 4 + r];
                float rv = 10.0f / fmaxf(sqrtf(tot), 1e-12f);
                acc[si][0][r] *= rv;
                acc[si][1][r] *= rv;
            }
    }

    // column softmax over s (no max pass: |logit| <= 10, exp safe in fp32).
    // column q = wq + qi*16 + lr; own 32 rows reduce (xor 16,32) + exchange with w^2.
    const int len = tlen[t];
    const float thr = 1.0f / (float)len;
    float csum[2];
    {
        float* colp = (float*)(RK + 16896);
#pragma unroll
        for (int qi = 0; qi < 2; ++qi) {
            float cs = 0.0f;
#pragma unroll
            for (int si = 0; si < 2; ++si)
#pragma unroll
                for (int r = 0; r < 4; ++r) {
                    int s = wsr + si * 16 + lk * 4 + r;
                    float e = (s < len) ? __expf(acc[si][qi][r]) : 0.0f;
                    acc[si][qi][r] = e;
                    cs += e;
                }
            cs += __shfl_xor(cs, 16);
            cs += __shfl_xor(cs, 32);
            csum[qi] = cs;
        }
        if (lk == 0) {
            colp[w * 32 + lr] = csum[0];
            colp[w * 32 + 16 + lr] = csum[1];
        }
        __syncthreads();
        const float* pcp = (const float*)(RK + 16896) + (w ^ 2) * 32;
        csum[0] += pcp[lr];
        csum[1] += pcp[16 + lr];
    }
    // p = e/sum; focal partial sk
    float skv[2];
    {
        float* colp2 = (float*)(RK + 16896) + 128;
#pragma unroll
        for (int qi = 0; qi < 2; ++qi) {
            float inv = 1.0f / csum[qi];
            float sk = 0.0f;
#pragma unroll
            for (int si = 0; si < 2; ++si)
#pragma unroll
                for (int r = 0; r < 4; ++r) {
                    float p = acc[si][qi][r] * inv;
                    acc[si][qi][r] = p;
                    if (p > thr) sk += p;
                }
            sk += __shfl_xor(sk, 16);
            sk += __shfl_xor(sk, 32);
            skv[qi] = sk;
        }
        if (lk == 0) {
            colp2[w * 32 + lr] = skv[0];
            colp2[w * 32 + 16 + lr] = skv[1];
        }
        __syncthreads();
        const float* pk = (const float*)(RK + 16896) + 128 + (w ^ 2) * 32;
        skv[0] += pk[lr];
        skv[1] += pk[16 + lr];
    }

    // write P (bf16 hi/lo) straight from registers, swizzled chunk format
    {
        ushort_t* Ph = (ushort_t*)RK;
        ushort_t* Pl = (ushort_t*)(RK + 8192);
#pragma unroll
        for (int si = 0; si < 2; ++si)
#pragma unroll
            for (int qi = 0; qi < 2; ++qi) {
                int q = wq + qi * 16 + lr;
                float iv2 = 1.0f / skv[qi];
                s16x4 vh, vl;
#pragma unroll
                for (int r = 0; r < 4; ++r) {
                    float p = acc[si][qi][r];
                    float pv = (p > thr) ? p * iv2 : 0.0f;
                    if (q >= Q_N) pv = 0.0f;
                    ushort_t hh, ll;
                    split_bf16(pv, hh, ll);
                    vh[r] = (short)hh;
                    vl[r] = (short)ll;
                }
                int s0 = wsr + si * 16 + lk * 4;
                int cidx = s0 >> 3;
                int off = q * 64 + ((cidx ^ (q & 7)) << 3) + (s0 & 7);
                *(s16x4*)(Ph + off) = vh;
                *(s16x4*)(Pl + off) = vl;
            }
    }
    __syncthreads();

    // ============ Phase 3 (swapped operands): weiT[d][q] = Vt(d,s) x P(q,s) ============
    f32x4 acc2[4][4];
#pragma unroll
    for (int a = 0; a < 4; ++a)
#pragma unroll
        for (int b2 = 0; b2 < 4; ++b2) acc2[a][b2] = (f32x4){0.f, 0.f, 0.f, 0.f};
    {
        const ushort_t* vH = vfh + ((size_t)t << 14) + (size_t)w * 4096;
        const ushort_t* vL = vfl + ((size_t)t << 14) + (size_t)w * 4096;
        const ushort_t* PH = (const ushort_t*)RK;
        const ushort_t* PL = (const ushort_t*)(RK + 8192);
#pragma unroll
        for (int k0g = 0; k0g < 2; ++k0g) {
#pragma unroll
            for (int md = 0; md < 4; ++md) {
                int vo = md * 1024 + k0g * 512 + lane * 8;
                short8 vh = *(const short8*)(vH + vo);
                short8 vl = *(const short8*)(vL + vo);
#pragma unroll
                for (int nq = 0; nq < 4; ++nq) {
                    int qrow = nq * 16 + lr;
                    int o = qrow * 64 + (((k0g * 4 + lk) ^ (qrow & 7)) << 3);
                    short8 ph = *(const short8*)(PH + o);
                    short8 pl = *(const short8*)(PL + o);
                    acc2[md][nq] = __builtin_amdgcn_mfma_f32_16x16x32_bf16(vh, ph, acc2[md][nq], 0, 0, 0);
                    acc2[md][nq] = __builtin_amdgcn_mfma_f32_16x16x32_bf16(vl, ph, acc2[md][nq], 0, 0, 0);
                    acc2[md][nq] = __builtin_amdgcn_mfma_f32_16x16x32_bf16(vh, pl, acc2[md][nq], 0, 0, 0);
                }
            }
        }
    }

    // ===== Epilogue: d-reduction over regs (md,r) + 2 shuffles (lk) + LDS (w) =====
    {
        float* wsq = (float*)(RK + 17920);
        float* wdv = (float*)(RK + 18944);
        const float* vPb = vP + ((((size_t)i * 4 + w) * 64 + lane) << 6);
#pragma unroll
        for (int nq = 0; nq < 4; ++nq) {
            float s2 = 0.0f, dv = 0.0f;
#pragma unroll
            for (int md = 0; md < 4; ++md) {
                f32x4 vv = *(const f32x4*)(vPb + nq * 16 + md * 4);
#pragma unroll
                for (int r = 0; r < 4; ++r) {
                    float wv = acc2[md][nq][r];
                    s2 += wv * wv;
                    dv += wv * vv[r];
                }
            }
            s2 += __shfl_xor(s2, 16);
            s2 += __shfl_xor(s2, 32);
            dv += __shfl_xor(dv, 16);
            dv += __shfl_xor(dv, 32);
            if (lane < 16) {
                wsq[w * 64 + nq * 16 + lane] = s2;
                wdv[w * 64 + nq * 16 + lane] = dv;
            }
        }
    }
    __syncthreads();
    if (tid < 64) {
        const float* wsq = (const float*)(RK + 17920);
        const float* wdv = (const float*)(RK + 18944);
        int q = tid;
        float s2 = 0.0f, dv = 0.0f;
#pragma unroll
        for (int ww = 0; ww < 4; ++ww) {
            s2 += wsq[ww * 64 + q];
            dv += wdv[ww * 64 + q];
        }
        float sim = 0.0f;
        if (q < Q_N) {
            float wn = sqrtf(s2);
            float w12 = dv / fmaxf(wn, 1e-12f);
            float wnn = wn / fmaxf(wn, 1e-12f);
            float denom = fmaxf(vnorm[i * 64 + q] * wnn, 1e-8f);
            sim = w12 / denom;
        }
        sim = waveReduceSum64(sim);
        if (tid == 0) out[(size_t)i * T_N + t] = sim * (1.0f / (float)Q_N);
    }
}

extern "C" void kernel_launch(void* const* d_in, const int* in_sizes, int n_in,
                              void* d_out, int out_size, void* d_ws, size_t ws_size,
                              hipStream_t stream) {
    const float* img_query = (const float*)d_in[0];  // [I,49,D]
    const float* img_value = (const float*)d_in[1];  // [I,49,D]
    const float* text_key  = (const float*)d_in[2];  // [T,64,D]
    const float* text_val  = (const float*)d_in[3];  // [T,64,D]
    const int*   text_len  = (const int*)d_in[4];    // [T]
    float* out = (float*)d_out;

    const size_t NPAD = (size_t)64 * 64 * 256;       // 1,048,576 elements
    ushort_t* qfh = (ushort_t*)d_ws;
    ushort_t* qfl = qfh + NPAD;
    ushort_t* kfh = qfl + NPAD;
    ushort_t* kfl = kfh + NPAD;
    ushort_t* vfh = kfl + NPAD;
    ushort_t* vfl = vfh + NPAD;
    float* vnorm  = (float*)(vfl + NPAD);            // [I*64]
    float* vP     = vnorm + I_N * 64;                // [I][4][64][64] = 4 MB

    prep_all<<<8960, 256, 0, stream>>>(img_query, img_value, text_key, text_val,
                                       qfh, qfl, kfh, kfl, vfh, vfl, vP, vnorm);

    i2t_mfma<<<T_N * I_N, 256, 0, stream>>>(kfh, kfl, qfh, qfl, vfh, vfl,
                                            vP, vnorm, text_len, out);
}

// Round 20
// 103.969 us; speedup vs baseline: 1.0546x; 1.0546x over previous
//
#include <hip/hip_runtime.h>
#include <math.h>

#define I_N 64
#define Q_N 49
#define T_N 64
#define S_N 64
#define D_N 256

typedef __attribute__((ext_vector_type(8))) short short8;
typedef __attribute__((ext_vector_type(4))) float f32x4;
typedef unsigned short ushort_t;

__device__ __forceinline__ float waveReduceSum64(float v) {
    v += __shfl_xor(v, 1);
    v += __shfl_xor(v, 2);
    v += __shfl_xor(v, 4);
    v += __shfl_xor(v, 8);
    v += __shfl_xor(v, 16);
    v += __shfl_xor(v, 32);
    return v;
}

__device__ __forceinline__ ushort_t f2bf(float x) {
    unsigned u = __builtin_bit_cast(unsigned, x);
    unsigned r = (u + 0x7fffu + ((u >> 16) & 1u)) >> 16;
    return (ushort_t)r;
}
__device__ __forceinline__ float bf2f(ushort_t h) {
    unsigned u = ((unsigned)h) << 16;
    return __builtin_bit_cast(float, u);
}
__device__ __forceinline__ void split_bf16(float x, ushort_t& h, ushort_t& l) {
    h = f2bf(x);
    l = f2bf(x - bf2f(h));
}

// ---------- fused prep: one launch, routed by blockIdx ----------
// b in [0,8192):    normalize img-query rows (b<4096) / text-key rows, split hi/lo,
//                   fragment-major Xf[hi][grp4][k8][lane][e]; also ||img_value||.
// b in [8192,8448): text value -> fragment-major transposed Vf (t = (b-8192)>>2, d-slab).
// b in [8448,8960): permuted img_value vP; i = (b-8448)>>3, 8 reps per block.
__global__ void prep_all(const float* __restrict__ q_in, const float* __restrict__ v_in,
                         const float* __restrict__ k_in, const float* __restrict__ tv,
                         ushort_t* __restrict__ qfh, ushort_t* __restrict__ qfl,
                         ushort_t* __restrict__ kfh, ushort_t* __restrict__ kfl,
                         ushort_t* __restrict__ vfh, ushort_t* __restrict__ vfl,
                         float* __restrict__ vP, float* __restrict__ vnorm) {
    __shared__ float tile[64][65];
    __shared__ float ws[8];
    int b = blockIdx.x;
    int tid = threadIdx.x;

    if (b < 8192) {
        int isimg = (b < 4096) ? 1 : 0;
        int row = isimg ? b : (b - 4096);      // hi*64 + lo
        int hi = row >> 6, lo = row & 63;
        float x = 0.0f, vv = 0.0f;
        if (isimg) {
            if (lo < Q_N) {
                size_t base = ((size_t)hi * Q_N + lo) * D_N + tid;
                x = q_in[base];
                vv = v_in[base];
            }
        } else {
            x = k_in[(size_t)row * D_N + tid];
        }
        float s1 = waveReduceSum64(x * x);
        float s2 = waveReduceSum64(vv * vv);
        int wv = tid >> 6, ln = tid & 63;
        if (ln == 0) { ws[wv] = s1; ws[4 + wv] = s2; }
        __syncthreads();
        float n1 = sqrtf(ws[0] + ws[1] + ws[2] + ws[3]);
        float xn = x / fmaxf(n1, 1e-12f);
        ushort_t h, l;
        split_bf16(xn, h, l);
        size_t off = ((size_t)hi << 14) + (size_t)((((lo >> 4) * 8 + (tid >> 5))) << 9)
                   + (size_t)(((((tid >> 3) & 3) * 16 + (lo & 15))) << 3) + (tid & 7);
        if (isimg) {
            qfh[off] = h;
            qfl[off] = l;
            if (tid == 0) vnorm[row] = sqrtf(ws[4] + ws[5] + ws[6] + ws[7]);
        } else {
            kfh[off] = h;
            kfl[off] = l;
        }
    } else if (b < 8448) {
        int bb = b - 8192;
        int t = bb >> 2;
        int d0 = (bb & 3) * 64;
        const float* src = tv + ((size_t)t << 14) + d0;
        ushort_t* dh = vfh + ((size_t)t << 14);
        ushort_t* dl = vfl + ((size_t)t << 14);
#pragma unroll
        for (int r = 0; r < 16; ++r) {
            int idx = r * 256 + tid;
            int s = idx >> 6, d = idx & 63;
            tile[s][d] = src[s * D_N + d];
        }
        __syncthreads();
#pragma unroll
        for (int r = 0; r < 16; ++r) {
            int idx = r * 256 + tid;
            int d = idx >> 6, s = idx & 63;
            int dg = d0 + d;
            float x = tile[s][d];
            ushort_t h, l;
            split_bf16(x, h, l);
            int dgrp = dg >> 4, lrd = dg & 15;
            int k0g = s >> 5, lk3 = (s >> 3) & 3, e = s & 7;
            size_t off = (size_t)(dgrp << 10) + (k0g << 9) + ((lk3 * 16 + lrd) << 3) + e;
            dh[off] = h;
            dl[off] = l;
        }
    } else {
        int bb = b - 8448;
        int i = bb >> 3;
        int sub = bb & 7;
        const float* src = v_in + (size_t)i * Q_N * D_N;
        float* dst = vP + ((size_t)i << 14);
        // vP[i][w4][lane64][nq4][md4][r4] = vimg[i][q=nq*16+(lane&15)][d=w*64+md*16+(lane>>4)*4+r]
#pragma unroll
        for (int r2 = 0; r2 < 8; ++r2) {
            int rep = sub * 8 + r2;             // 0..63
            int o = rep * 256 + tid;            // flat index into vP[i]
            int r = o & 3;
            int md = (o >> 2) & 3;
            int nq = (o >> 4) & 3;
            int lane = (o >> 6) & 63;
            int w = o >> 12;
            int lr = lane & 15, lk = lane >> 4;
            int q = nq * 16 + lr;
            int d = w * 64 + md * 16 + lk * 4 + r;
            dst[o] = (q < Q_N) ? src[q * D_N + d] : 0.0f;
        }
    }
}

// ---------- main: one 256-thread block (4 waves) per (t,i) — measured optimum ----------
__launch_bounds__(256, 4)
__global__ void i2t_mfma(const ushort_t* __restrict__ kfh, const ushort_t* __restrict__ kfl,
                         const ushort_t* __restrict__ qfh, const ushort_t* __restrict__ qfl,
                         const ushort_t* __restrict__ vfh, const ushort_t* __restrict__ vfl,
                         const float* __restrict__ vP,
                         const float* __restrict__ vnorm,
                         const int* __restrict__ tlen,
                         float* __restrict__ out)
{
    // As fp32 [64][65] @0 (16640) | rinv @16640 (256) | Ph @16896 (8K) | Pl @25088 (8K)
    // epilogue overlay on As region: wsq @0 (1K), wdv @1024 (1K)
    __shared__ __align__(16) unsigned char RK[33280];

    const int bid = blockIdx.x;
    const int xcd = bid & 7;
    const int j = bid >> 3;
    const int t = (xcd << 3) | (j & 7);   // each XCD owns 8 t values -> K/Vf L2-resident
    const int i = j >> 3;

    const int tid = threadIdx.x;
    const int lane = tid & 63;
    const int w = tid >> 6;        // wave 0..3
    const int lr = lane & 15;
    const int lk = lane >> 4;

    // ============ Phase 1: attn[s][q] = K.Q^T, wave tile = 32s x 32q (2x2 subtiles) ====
    const int wsr = (w >> 1) * 32;    // s-base
    const int wq  = (w & 1) * 32;     // q-base
    f32x4 acc[2][2];
#pragma unroll
    for (int a = 0; a < 2; ++a)
#pragma unroll
        for (int b2 = 0; b2 < 2; ++b2) acc[a][b2] = (f32x4){0.f, 0.f, 0.f, 0.f};
    {
        const ushort_t* kH = kfh + ((size_t)t << 14) + (size_t)(w >> 1) * 8192;
        const ushort_t* kL = kfl + ((size_t)t << 14) + (size_t)(w >> 1) * 8192;
        const ushort_t* qH = qfh + ((size_t)i << 14) + (size_t)(w & 1) * 8192;
        const ushort_t* qL = qfl + ((size_t)i << 14) + (size_t)(w & 1) * 8192;
#pragma unroll
        for (int k8 = 0; k8 < 8; ++k8) {
            int fo = k8 * 512 + lane * 8;
            short8 aH0 = *(const short8*)(kH + fo);
            short8 aL0 = *(const short8*)(kL + fo);
            short8 aH1 = *(const short8*)(kH + 4096 + fo);
            short8 aL1 = *(const short8*)(kL + 4096 + fo);
            short8 bH0 = *(const short8*)(qH + fo);
            short8 bL0 = *(const short8*)(qL + fo);
            short8 bH1 = *(const short8*)(qH + 4096 + fo);
            short8 bL1 = *(const short8*)(qL + 4096 + fo);
            acc[0][0] = __builtin_amdgcn_mfma_f32_16x16x32_bf16(aH0, bH0, acc[0][0], 0, 0, 0);
            acc[0][1] = __builtin_amdgcn_mfma_f32_16x16x32_bf16(aH0, bH1, acc[0][1], 0, 0, 0);
            acc[1][0] = __builtin_amdgcn_mfma_f32_16x16x32_bf16(aH1, bH0, acc[1][0], 0, 0, 0);
            acc[1][1] = __builtin_amdgcn_mfma_f32_16x16x32_bf16(aH1, bH1, acc[1][1], 0, 0, 0);
            acc[0][0] = __builtin_amdgcn_mfma_f32_16x16x32_bf16(aH0, bL0, acc[0][0], 0, 0, 0);
            acc[0][1] = __builtin_amdgcn_mfma_f32_16x16x32_bf16(aH0, bL1, acc[0][1], 0, 0, 0);
            acc[1][0] = __builtin_amdgcn_mfma_f32_16x16x32_bf16(aH1, bL0, acc[1][0], 0, 0, 0);
            acc[1][1] = __builtin_amdgcn_mfma_f32_16x16x32_bf16(aH1, bL1, acc[1][1], 0, 0, 0);
            acc[0][0] = __builtin_amdgcn_mfma_f32_16x16x32_bf16(aL0, bH0, acc[0][0], 0, 0, 0);
            acc[0][1] = __builtin_amdgcn_mfma_f32_16x16x32_bf16(aL0, bH1, acc[0][1], 0, 0, 0);
            acc[1][0] = __builtin_amdgcn_mfma_f32_16x16x32_bf16(aL1, bH0, acc[1][0], 0, 0, 0);
            acc[1][1] = __builtin_amdgcn_mfma_f32_16x16x32_bf16(aL1, bH1, acc[1][1], 0, 0, 0);
        }
    }
    // LeakyReLU + As write
    {
        float* As = (float*)RK;
#pragma unroll
        for (int si = 0; si < 2; ++si)
#pragma unroll
            for (int qi = 0; qi < 2; ++qi)
#pragma unroll
                for (int r = 0; r < 4; ++r) {
                    int s = wsr + si * 16 + lk * 4 + r;
                    int q = wq + qi * 16 + lr;
                    float v = acc[si][qi][r];
                    v = (v > 0.0f) ? v : 0.1f * v;
                    As[s * 65 + q] = v;
                }
    }
    __syncthreads();

    // ================= Phase 2a: per-s l2norm over q (256 threads) =================
    {
        const float* As = (const float*)RK;
        float* rinv = (float*)(RK + 16640);
        int s = tid >> 2, part = tid & 3;
        float ss = 0.0f;
#pragma unroll
        for (int q0 = 0; q0 < 64; q0 += 4) {
            float v = As[s * 65 + q0 + part];
            ss += v * v;
        }
        ss += __shfl_xor(ss, 1);
        ss += __shfl_xor(ss, 2);
        if (part == 0) rinv[s] = 1.0f / fmaxf(sqrtf(ss), 1e-12f);
    }
    __syncthreads();

    // ================= Phase 2b: masked softmax + focal, write swizzled P ==========
    const int len = tlen[t];
    {
        const float* As = (const float*)RK;
        const float* rinv = (const float*)(RK + 16640);
        ushort_t* Ph = (ushort_t*)(RK + 16896);
        ushort_t* Pl = (ushort_t*)(RK + 25088);
        const float thr = 1.0f / (float)len;
        int q = tid >> 2, part = tid & 3;      // part handles s in [part*16, part*16+16)
        float logit[16];
        float m = -INFINITY;
#pragma unroll
        for (int k = 0; k < 16; ++k) {
            int s = part * 16 + k;
            float lg = (s < len) ? 10.0f * As[s * 65 + q] * rinv[s] : -INFINITY;
            logit[k] = lg;
            m = fmaxf(m, lg);
        }
        m = fmaxf(m, __shfl_xor(m, 1));
        m = fmaxf(m, __shfl_xor(m, 2));
        float p[16];
        float sum = 0.0f;
#pragma unroll
        for (int k = 0; k < 16; ++k) {
            int s = part * 16 + k;
            float e = (s < len) ? __expf(logit[k] - m) : 0.0f;
            p[k] = e;
            sum += e;
        }
        sum += __shfl_xor(sum, 1);
        sum += __shfl_xor(sum, 2);
        float inv = 1.0f / sum;
        float sk = 0.0f;
#pragma unroll
        for (int k = 0; k < 16; ++k) {
            p[k] *= inv;
            if (p[k] > thr) sk += p[k];
        }
        sk += __shfl_xor(sk, 1);
        sk += __shfl_xor(sk, 2);
        float iv2 = 1.0f / sk;

        ushort_t hh[16], ll[16];
#pragma unroll
        for (int k = 0; k < 16; ++k) {
            float pv = (p[k] > thr) ? p[k] * iv2 : 0.0f;
            if (q >= Q_N) pv = 0.0f;
            split_bf16(pv, hh[k], ll[k]);
        }
        int c0 = (2 * part) ^ (q & 7);
        int c1 = (2 * part + 1) ^ (q & 7);
        short8 v0, v1;
#pragma unroll
        for (int k = 0; k < 8; ++k) { v0[k] = (short)hh[k]; v1[k] = (short)hh[k + 8]; }
        *(short8*)(Ph + q * 64 + (c0 << 3)) = v0;
        *(short8*)(Ph + q * 64 + (c1 << 3)) = v1;
#pragma unroll
        for (int k = 0; k < 8; ++k) { v0[k] = (short)ll[k]; v1[k] = (short)ll[k + 8]; }
        *(short8*)(Pl + q * 64 + (c0 << 3)) = v0;
        *(short8*)(Pl + q * 64 + (c1 << 3)) = v1;
    }
    __syncthreads();

    // ============ Phase 3 (swapped operands): weiT[d][q] = Vt(d,s) x P(q,s) ============
    f32x4 acc2[4][4];
#pragma unroll
    for (int a = 0; a < 4; ++a)
#pragma unroll
        for (int b2 = 0; b2 < 4; ++b2) acc2[a][b2] = (f32x4){0.f, 0.f, 0.f, 0.f};
    {
        const ushort_t* vH = vfh + ((size_t)t << 14) + (size_t)w * 4096;
        const ushort_t* vL = vfl + ((size_t)t << 14) + (size_t)w * 4096;
        const ushort_t* PH = (const ushort_t*)(RK + 16896);
        const ushort_t* PL = (const ushort_t*)(RK + 25088);
#pragma unroll
        for (int k0g = 0; k0g < 2; ++k0g) {
#pragma unroll
            for (int md = 0; md < 4; ++md) {
                int vo = md * 1024 + k0g * 512 + lane * 8;
                short8 vh = *(const short8*)(vH + vo);
                short8 vl = *(const short8*)(vL + vo);
#pragma unroll
                for (int nq = 0; nq < 4; ++nq) {
                    int qrow = nq * 16 + lr;
                    int o = qrow * 64 + (((k0g * 4 + lk) ^ (qrow & 7)) << 3);
                    short8 ph = *(const short8*)(PH + o);
                    short8 pl = *(const short8*)(PL + o);
                    acc2[md][nq] = __builtin_amdgcn_mfma_f32_16x16x32_bf16(vh, ph, acc2[md][nq], 0, 0, 0);
                    acc2[md][nq] = __builtin_amdgcn_mfma_f32_16x16x32_bf16(vl, ph, acc2[md][nq], 0, 0, 0);
                    acc2[md][nq] = __builtin_amdgcn_mfma_f32_16x16x32_bf16(vh, pl, acc2[md][nq], 0, 0, 0);
                }
            }
        }
    }

    // ===== Epilogue: d-reduction over regs (md,r) + 2 shuffles (lk) + LDS (w) =====
    {
        float* wsq = (float*)RK;
        float* wdv = (float*)(RK + 1024);
        const float* vPb = vP + ((((size_t)i * 4 + w) * 64 + lane) << 6);
#pragma unroll
        for (int nq = 0; nq < 4; ++nq) {
            float s2 = 0.0f, dv = 0.0f;
#pragma unroll
            for (int md = 0; md < 4; ++md) {
                f32x4 vv = *(const f32x4*)(vPb + nq * 16 + md * 4);
#pragma unroll
                for (int r = 0; r < 4; ++r) {
                    float wv = acc2[md][nq][r];
                    s2 += wv * wv;
                    dv += wv * vv[r];
                }
            }
            s2 += __shfl_xor(s2, 16);
            s2 += __shfl_xor(s2, 32);
            dv += __shfl_xor(dv, 16);
            dv += __shfl_xor(dv, 32);
            if (lane < 16) {
                wsq[w * 64 + nq * 16 + lane] = s2;
                wdv[w * 64 + nq * 16 + lane] = dv;
            }
        }
    }
    __syncthreads();
    if (tid < 64) {
        const float* wsq = (const float*)RK;
        const float* wdv = (const float*)(RK + 1024);
        int q = tid;
        float s2 = 0.0f, dv = 0.0f;
#pragma unroll
        for (int ww = 0; ww < 4; ++ww) {
            s2 += wsq[ww * 64 + q];
            dv += wdv[ww * 64 + q];
        }
        float sim = 0.0f;
        if (q < Q_N) {
            float wn = sqrtf(s2);
            float w12 = dv / fmaxf(wn, 1e-12f);
            float wnn = wn / fmaxf(wn, 1e-12f);
            float denom = fmaxf(vnorm[i * 64 + q] * wnn, 1e-8f);
            sim = w12 / denom;
        }
        sim = waveReduceSum64(sim);
        if (tid == 0) out[(size_t)i * T_N + t] = sim * (1.0f / (float)Q_N);
    }
}

extern "C" void kernel_launch(void* const* d_in, const int* in_sizes, int n_in,
                              void* d_out, int out_size, void* d_ws, size_t ws_size,
                              hipStream_t stream) {
    const float* img_query = (const float*)d_in[0];  // [I,49,D]
    const float* img_value = (const float*)d_in[1];  // [I,49,D]
    const float* text_key  = (const float*)d_in[2];  // [T,64,D]
    const float* text_val  = (const float*)d_in[3];  // [T,64,D]
    const int*   text_len  = (const int*)d_in[4];    // [T]
    float* out = (float*)d_out;

    const size_t NPAD = (size_t)64 * 64 * 256;       // 1,048,576 elements
    ushort_t* qfh = (ushort_t*)d_ws;
    ushort_t* qfl = qfh + NPAD;
    ushort_t* kfh = qfl + NPAD;
    ushort_t* kfl = kfh + NPAD;
    ushort_t* vfh = kfl + NPAD;
    ushort_t* vfl = vfh + NPAD;
    float* vnorm  = (float*)(vfl + NPAD);            // [I*64]
    float* vP     = vnorm + I_N * 64;                // [I][4][64][64] = 4 MB

    prep_all<<<8960, 256, 0, stream>>>(img_query, img_value, text_key, text_val,
                                       qfh, qfl, kfh, kfl, vfh, vfl, vP, vnorm);

    i2t_mfma<<<T_N * I_N, 256, 0, stream>>>(kfh, kfl, qfh, qfl, vfh, vfl,
                                            vP, vnorm, text_len, out);
}